// Round 1
// baseline (50.209 us; speedup 1.0000x reference)
//
#include <hip/hip_runtime.h>

// SmoothnessLoss: error = sum_{c,h,w} x*(1 - cnt(h,w)*w) / (H*W)
// cnt(h,w) = nh*nw - 1, nh = 3-(h==0)-(h==H-1), nw = 3-(w==0)-(w==W-1).
// Derivation: sum over pixels of the 8-neighbor weighted sum counts each
// wx[y,x'] once per valid neighbor slot == size of its own neighborhood.

#define HDIM 4096
#define WDIM 4096
#define NBLOCKS 2048
#define NTHREADS 256

__global__ __launch_bounds__(NTHREADS) void smooth_partial_kernel(
    const float4* __restrict__ x4,
    const float4* __restrict__ w4,
    double* __restrict__ partial,
    int n4)
{
    int tid = blockIdx.x * blockDim.x + threadIdx.x;
    int stride = gridDim.x * blockDim.x;

    double acc = 0.0;
    for (int i = tid; i < n4; i += stride) {
        float4 xv = x4[i];
        float4 wv = w4[i];
        int e  = i << 2;                 // flat element index of .x
        int ww = e & (WDIM - 1);         // column of .x (W divisible by 4)
        int h  = (e >> 12) & (HDIM - 1); // row

        float nh  = 3.0f - (h == 0) - (h == HDIM - 1);
        float nw0 = (ww == 0)        ? 2.0f : 3.0f;  // column ww
        float nw3 = (ww == WDIM - 4) ? 2.0f : 3.0f;  // column ww+3 == W-1

        float s;
        s  = xv.x * (1.0f - (nh * nw0  - 1.0f) * wv.x);
        s += xv.y * (1.0f - (nh * 3.0f - 1.0f) * wv.y);
        s += xv.z * (1.0f - (nh * 3.0f - 1.0f) * wv.z);
        s += xv.w * (1.0f - (nh * nw3  - 1.0f) * wv.w);
        acc += (double)s;
    }

    // wave(64) butterfly reduce (double shuffles as 2x32b)
    for (int off = 32; off > 0; off >>= 1)
        acc += __shfl_down(acc, off, 64);

    __shared__ double lds[NTHREADS / 64];
    int lane = threadIdx.x & 63;
    int wid  = threadIdx.x >> 6;
    if (lane == 0) lds[wid] = acc;
    __syncthreads();

    if (threadIdx.x == 0) {
        double s = 0.0;
        #pragma unroll
        for (int j = 0; j < NTHREADS / 64; ++j) s += lds[j];
        partial[blockIdx.x] = s;
    }
}

__global__ __launch_bounds__(NTHREADS) void smooth_final_kernel(
    const double* __restrict__ partial,
    int n,
    float* __restrict__ out)
{
    double acc = 0.0;
    for (int i = threadIdx.x; i < n; i += NTHREADS) acc += partial[i];

    for (int off = 32; off > 0; off >>= 1)
        acc += __shfl_down(acc, off, 64);

    __shared__ double lds[NTHREADS / 64];
    int lane = threadIdx.x & 63;
    int wid  = threadIdx.x >> 6;
    if (lane == 0) lds[wid] = acc;
    __syncthreads();

    if (threadIdx.x == 0) {
        double s = 0.0;
        #pragma unroll
        for (int j = 0; j < NTHREADS / 64; ++j) s += lds[j];
        out[0] = (float)(s / ((double)HDIM * (double)WDIM));
    }
}

extern "C" void kernel_launch(void* const* d_in, const int* in_sizes, int n_in,
                              void* d_out, int out_size, void* d_ws, size_t ws_size,
                              hipStream_t stream) {
    const float4* x4 = (const float4*)d_in[0];
    const float4* w4 = (const float4*)d_in[1];
    float* out = (float*)d_out;
    double* partial = (double*)d_ws;   // NBLOCKS doubles = 16 KB

    int n4 = in_sizes[0] / 4;          // 2*4096*4096/4 = 8388608 float4s

    smooth_partial_kernel<<<NBLOCKS, NTHREADS, 0, stream>>>(x4, w4, partial, n4);
    smooth_final_kernel<<<1, NTHREADS, 0, stream>>>(partial, NBLOCKS, out);
}

// Round 2
// 48.473 us; speedup vs baseline: 1.0358x; 1.0358x over previous
//
#include <hip/hip_runtime.h>

// SmoothnessLoss: error = sum_{c,h,w} x*(1 - cnt(h,w)*w) / (H*W)
// cnt(h,w) = nh*nw - 1, nh = 3-(h==0)-(h==H-1), nw = 3-(w==0)-(w==W-1).
// Derivation: summing the 8-neighbor gather over all pixels counts each
// wx[y,x'] once per valid neighbor slot == size of its own neighborhood.
//
// Geometry is fixed: 2*4096*4096 f32 elements = 8388608 float4s.
// Grid 2048x256 = 524288 threads -> exactly 16 float4s/thread (compile-time),
// enabling full unroll + deep MLP.

#define HDIM 4096
#define WDIM 4096
#define NBLOCKS 2048
#define NTHREADS 256
#define N4 ((2 * HDIM * WDIM) / 4)
#define STRIDE (NBLOCKS * NTHREADS)
#define ITERS (N4 / STRIDE)   // = 16

__global__ __launch_bounds__(NTHREADS) void smooth_partial_kernel(
    const float4* __restrict__ x4,
    const float4* __restrict__ w4,
    double* __restrict__ partial)
{
    int tid = blockIdx.x * blockDim.x + threadIdx.x;

    double acc0 = 0.0, acc1 = 0.0, acc2 = 0.0, acc3 = 0.0;

    #pragma unroll
    for (int it = 0; it < ITERS; ++it) {
        int i = tid + it * STRIDE;
        float4 xv = x4[i];
        float4 wv = w4[i];
        int e  = i << 2;                 // flat element index of .x
        int ww = e & (WDIM - 1);         // column of .x (W divisible by 4)
        int h  = (e >> 12) & (HDIM - 1); // row

        float nh  = 3.0f - (h == 0) - (h == HDIM - 1);
        float nw0 = (ww == 0)        ? 2.0f : 3.0f;  // column ww
        float nw3 = (ww == WDIM - 4) ? 2.0f : 3.0f;  // column ww+3 == W-1

        float s0 = xv.x * (1.0f - (nh * nw0  - 1.0f) * wv.x);
        float s1 = xv.y * (1.0f - (nh * 3.0f - 1.0f) * wv.y);
        float s2 = xv.z * (1.0f - (nh * 3.0f - 1.0f) * wv.z);
        float s3 = xv.w * (1.0f - (nh * nw3  - 1.0f) * wv.w);

        // 4 independent f64 chains to break accumulator latency dependency
        acc0 += (double)s0;
        acc1 += (double)s1;
        acc2 += (double)s2;
        acc3 += (double)s3;
    }

    double acc = (acc0 + acc1) + (acc2 + acc3);

    // wave(64) butterfly reduce
    for (int off = 32; off > 0; off >>= 1)
        acc += __shfl_down(acc, off, 64);

    __shared__ double lds[NTHREADS / 64];
    int lane = threadIdx.x & 63;
    int wid  = threadIdx.x >> 6;
    if (lane == 0) lds[wid] = acc;
    __syncthreads();

    if (threadIdx.x == 0) {
        double s = 0.0;
        #pragma unroll
        for (int j = 0; j < NTHREADS / 64; ++j) s += lds[j];
        partial[blockIdx.x] = s;
    }
}

__global__ __launch_bounds__(NTHREADS) void smooth_final_kernel(
    const double* __restrict__ partial,
    float* __restrict__ out)
{
    double acc = 0.0;
    for (int i = threadIdx.x; i < NBLOCKS; i += NTHREADS) acc += partial[i];

    for (int off = 32; off > 0; off >>= 1)
        acc += __shfl_down(acc, off, 64);

    __shared__ double lds[NTHREADS / 64];
    int lane = threadIdx.x & 63;
    int wid  = threadIdx.x >> 6;
    if (lane == 0) lds[wid] = acc;
    __syncthreads();

    if (threadIdx.x == 0) {
        double s = 0.0;
        #pragma unroll
        for (int j = 0; j < NTHREADS / 64; ++j) s += lds[j];
        out[0] = (float)(s / ((double)HDIM * (double)WDIM));
    }
}

extern "C" void kernel_launch(void* const* d_in, const int* in_sizes, int n_in,
                              void* d_out, int out_size, void* d_ws, size_t ws_size,
                              hipStream_t stream) {
    const float4* x4 = (const float4*)d_in[0];
    const float4* w4 = (const float4*)d_in[1];
    float* out = (float*)d_out;
    double* partial = (double*)d_ws;   // NBLOCKS doubles = 16 KB

    (void)in_sizes; (void)n_in; (void)out_size; (void)ws_size;

    smooth_partial_kernel<<<NBLOCKS, NTHREADS, 0, stream>>>(x4, w4, partial);
    smooth_final_kernel<<<1, NTHREADS, 0, stream>>>(partial, out);
}